// Round 7
// baseline (427.059 us; speedup 1.0000x reference)
//
#include <hip/hip_runtime.h>
#include <hip/hip_fp16.h>

#define NB 8
#define NC 256
#define NHW 1024
#define NI 8
#define NH 4
#define HD 64
#define EPS 1e-12f
#define QSC  64.0f
#define QSCI 0.015625f

typedef _Float16 f16;
typedef __attribute__((ext_vector_type(8))) _Float16 half8;
typedef __attribute__((ext_vector_type(4))) float floatx4;

union H8 { half8 h8; __half2 h2[4]; uint4 u4; };
union H4 { uint2 u2; __half2 h2[2]; };

// ---------------- K1a: mask logit partials over 32-c chunks (256 blocks) ----------------
__global__ __launch_bounds__(256) void k_mask_part(
    const float* __restrict__ x, const float* __restrict__ w_inst,
    float* __restrict__ part_m)
{
    __shared__ float w_s[NI][32];
    int nt = blockIdx.x, b = blockIdx.y, cc = blockIdx.z;
    int tid = threadIdx.x;
    w_s[tid >> 5][tid & 31] = w_inst[(tid >> 5)*NC + cc*32 + (tid & 31)];
    __syncthreads();
    int n = nt*256 + tid;
    const float* xp = x + ((size_t)(b*NC + cc*32))*NHW + n;
    float acc[NI] = {};
    for (int c = 0; c < 32; ++c) {
        float xv = xp[(size_t)c*NHW];
#pragma unroll
        for (int i = 0; i < NI; ++i) acc[i] = fmaf(w_s[i][c], xv, acc[i]);
    }
#pragma unroll
    for (int i = 0; i < NI; ++i)
        part_m[((size_t)(cc*NI + i)*NB + b)*NHW + n] = acc[i];
}

// ---------------- K1b: combine + softmax over instances ----------------
__global__ __launch_bounds__(256) void k_mask_comb(
    const float* __restrict__ part_m, const float* __restrict__ b_inst,
    float* __restrict__ masks)
{
    int nt = blockIdx.x, b = blockIdx.y;
    int n = nt*256 + threadIdx.x;
    float a[NI];
#pragma unroll
    for (int i = 0; i < NI; ++i) {
        float s = b_inst[i];
#pragma unroll
        for (int cc = 0; cc < 8; ++cc)
            s += part_m[((size_t)(cc*NI + i)*NB + b)*NHW + n];
        a[i] = s;
    }
    float m = a[0];
#pragma unroll
    for (int i = 1; i < NI; ++i) m = fmaxf(m, a[i]);
    float ssum = 0.f;
#pragma unroll
    for (int i = 0; i < NI; ++i) { a[i] = __expf(a[i]-m); ssum += a[i]; }
    float inv = 1.0f/ssum;
#pragma unroll
    for (int i = 0; i < NI; ++i) masks[((size_t)i*NB + b)*NHW + n] = a[i]*inv;
}

// ---------------- K2: G = W*x, one matrix per block (768 blocks = 3/CU) ----------------
__global__ __launch_bounds__(256,3) void k_gemm1(
    const float* __restrict__ x,
    const float* __restrict__ wq, const float* __restrict__ wk, const float* __restrict__ wv,
    f16* __restrict__ Gqt, f16* __restrict__ Gkt, f16* __restrict__ Gv)
{
    __shared__ __align__(16) float feat_s[32][128];
    __shared__ __align__(16) float w_s[32][68];
    int tid = threadIdx.x;
    int nt = blockIdx.x, ot = blockIdx.y;
    int m = blockIdx.z >> 3, b = blockIdx.z & 7;
    const float* wsel = (m == 0) ? wq : (m == 1) ? wk : wv;
    int o0 = ot*64, n0 = nt*128;
    int og = tid >> 5;
    int nl = tid & 31;
    int nn = tid & 127;
    int ch = tid >> 7;
    const float* xb = x + ((size_t)b*NC)*NHW + n0;
    float acc[8][4] = {};
    for (int c0 = 0; c0 < NC; c0 += 32) {
        __syncthreads();
#pragma unroll
        for (int r=0;r<16;r++) {
            int cc = 2*r + ch;
            feat_s[cc][nn] = xb[(size_t)(c0+cc)*NHW + nn];
        }
        {
            int cw = tid & 31;
#pragma unroll
            for (int r=0;r<8;r++) {
                int oo = 8*r + og;
                w_s[cw][oo] = wsel[(size_t)(o0+oo)*NC + c0 + cw];
            }
        }
        __syncthreads();
#pragma unroll 8
        for (int c=0;c<32;c++) {
            float4 f4 = *(const float4*)&feat_s[c][nl*4];
            float4 a0 = *(const float4*)&w_s[c][og*8];
            float4 a1 = *(const float4*)&w_s[c][og*8+4];
            float f[4] = {f4.x,f4.y,f4.z,f4.w};
            float w8[8] = {a0.x,a0.y,a0.z,a0.w,a1.x,a1.y,a1.z,a1.w};
#pragma unroll
            for (int io=0;io<8;io++)
#pragma unroll
                for (int in=0;in<4;in++)
                    acc[io][in] = fmaf(w8[io], f[in], acc[io][in]);
        }
    }
    if (m < 2) {
        f16* Gt = (m == 0) ? Gqt : Gkt;
#pragma unroll
        for (int in=0;in<4;in++) {
            int n = n0 + nl*4 + in;
            H8 q;
#pragma unroll
            for (int t=0;t<4;t++)
                q.h2[t] = __floats2half2_rn(acc[2*t][in], acc[2*t+1][in]);
            *(uint4*)(Gt + ((size_t)b*NHW + n)*NC + o0 + og*8) = q.u4;
        }
    } else {
#pragma unroll
        for (int io=0;io<8;io++) {
            int o = o0 + og*8 + io;
            H4 v;
            v.h2[0] = __floats2half2_rn(acc[io][0], acc[io][1]);
            v.h2[1] = __floats2half2_rn(acc[io][2], acc[io][3]);
            *(uint2*)(Gv + ((size_t)b*NC + o)*NHW + n0 + nl*4) = v.u2;
        }
    }
}

// ---------------- K3a: norm partials over 32-n chunks (256 blocks) ----------------
__global__ __launch_bounds__(256) void k_norm_part(
    const f16* __restrict__ Gqt, const f16* __restrict__ Gkt,
    const float* __restrict__ masks,
    const float* __restrict__ bq, const float* __restrict__ bk,
    float* __restrict__ part_nq, float* __restrict__ part_nk)
{
    __shared__ float m_s[NI][32];
    int nc = blockIdx.x, b = blockIdx.y;
    int c = threadIdx.x;
    int n0 = nc*32;
    m_s[c >> 5][c & 31] = masks[((size_t)(c >> 5)*NB + b)*NHW + n0 + (c & 31)];
    __syncthreads();
    float bqv = bq[c], bkv = bk[c];
    const f16* gq = Gqt + ((size_t)b*NHW + n0)*NC + c;
    const f16* gk = Gkt + ((size_t)b*NHW + n0)*NC + c;
    float aq[NI] = {}, ak[NI] = {};
    for (int t = 0; t < 32; ++t) {
        float g1 = (float)gq[(size_t)t*NC];
        float g2 = (float)gk[(size_t)t*NC];
#pragma unroll
        for (int i = 0; i < NI; ++i) {
            float mm = m_s[i][t];
            float e = fmaf(mm, g1, bqv); aq[i] = fmaf(e, e, aq[i]);
            e = fmaf(mm, g2, bkv);       ak[i] = fmaf(e, e, ak[i]);
        }
    }
#pragma unroll
    for (int i = 0; i < NI; ++i) {
        part_nq[((size_t)(nc*NI + i)*NB + b)*NC + c] = aq[i];
        part_nk[((size_t)(nc*NI + i)*NB + b)*NC + c] = ak[i];
    }
}

// ---------------- K3b: finalize scales (64 blocks) ----------------
__global__ __launch_bounds__(256) void k_norm_fin(
    const float* __restrict__ part_nq, const float* __restrict__ part_nk,
    float* __restrict__ scale_q, float* __restrict__ scale_k)
{
    int b = blockIdx.x, i = blockIdx.y, c = threadIdx.x;
    float sq = 0.f, sk = 0.f;
#pragma unroll
    for (int nc = 0; nc < 32; ++nc) {
        sq += part_nq[((size_t)(nc*NI + i)*NB + b)*NC + c];
        sk += part_nk[((size_t)(nc*NI + i)*NB + b)*NC + c];
    }
    scale_q[((size_t)i*NB + b)*NC + c] = 0.125f / fmaxf(sqrtf(sq), EPS);
    scale_k[((size_t)i*NB + b)*NC + c] = 1.0f   / fmaxf(sqrtf(sk), EPS);
}

// ---------------- K4: fused attention v5 — barrier-free j-loop ----------------
// grid 1024 (b=bid&7 XCD pin), block 512 = 8 waves, wave w = instance w.
// K/V A-frags loaded DIRECTLY from global (L1-shared by all 8 waves; per-(b,h)
// slice 256 KB = L2-resident). LDS only for the per-wave P' transpose (private ->
// zero barriers in the j-loop). Cross-instance sum: 3-barrier LDS tree overlaid on P'.
__global__ __launch_bounds__(512,4) void k_attn5(
    const f16* __restrict__ Gqt, const f16* __restrict__ Gkt, const f16* __restrict__ Gv,
    const float* __restrict__ masks,
    const float* __restrict__ bq, const float* __restrict__ bv,
    const float* __restrict__ scale_q, const float* __restrict__ scale_k,
    float* __restrict__ out)
{
    __shared__ __align__(16) char lds[36864];   // 8 x [32][72] f16 P' / 4 x [64][36] f32 red

    int tid = threadIdx.x, bid = blockIdx.x;
    int b = bid & 7, qt = (bid >> 3) & 31, h = bid >> 8;
    int qt0 = qt*32, c0 = h*HD;
    int w = tid >> 6, lane = tid & 63, quad = lane >> 4, l15 = lane & 15;
    f16* ph = (f16*)(lds + w*4608);             // this wave's [32 q][72 j]
    const float* mi = masks + ((size_t)w*NB + b)*NHW;

    // ---- hoisted q~ fragments (mask, bias, both scales, x64 folded) ----
    float mqf[2] = { mi[qt0 + l15], mi[qt0 + 16 + l15] };
    H8 qa[2][2];
    {
        const float* sqg = scale_q + ((size_t)w*NB + b)*NC;
        const float* skg = scale_k + ((size_t)w*NB + b)*NC;
        __half2 mq2[2] = { __float2half2_rn(mqf[0]), __float2half2_rn(mqf[1]) };
#pragma unroll
        for (int ks = 0; ks < 2; ++ks) {
            int cb = c0 + ks*32 + quad*8;
            float4 s0 = *(const float4*)(sqg + cb);
            float4 s1 = *(const float4*)(sqg + cb + 4);
            float4 t0 = *(const float4*)(skg + cb);
            float4 t1 = *(const float4*)(skg + cb + 4);
            float4 b0 = *(const float4*)(bq + cb);
            float4 b1 = *(const float4*)(bq + cb + 4);
            float ss[8] = {s0.x*t0.x*QSC, s0.y*t0.y*QSC, s0.z*t0.z*QSC, s0.w*t0.w*QSC,
                           s1.x*t1.x*QSC, s1.y*t1.y*QSC, s1.z*t1.z*QSC, s1.w*t1.w*QSC};
            float bb[8] = {b0.x*ss[0], b0.y*ss[1], b0.z*ss[2], b0.w*ss[3],
                           b1.x*ss[4], b1.y*ss[5], b1.z*ss[6], b1.w*ss[7]};
            __half2 sh[4], bh[4];
#pragma unroll
            for (int t = 0; t < 4; ++t) {
                sh[t] = __floats2half2_rn(ss[2*t], ss[2*t+1]);
                bh[t] = __floats2half2_rn(bb[2*t], bb[2*t+1]);
            }
            H8 g0, g1;
            g0.u4 = *(const uint4*)(Gqt + ((size_t)b*NHW + qt0 + l15)*NC + cb);
            g1.u4 = *(const uint4*)(Gqt + ((size_t)b*NHW + qt0 + 16 + l15)*NC + cb);
#pragma unroll
            for (int t = 0; t < 4; ++t) {
                qa[0][ks].h2[t] = __hfma2(mq2[0], __hmul2(g0.h2[t], sh[t]), bh[t]);
                qa[1][ks].h2[t] = __hfma2(mq2[1], __hmul2(g1.h2[t], sh[t]), bh[t]);
            }
        }
    }

    floatx4 acc[4][2];   // [cm][qi]; c = cm*16+quad*4+r, q = qi*16+l15
#pragma unroll
    for (int cm=0;cm<4;cm++)
#pragma unroll
        for (int qi=0;qi<2;qi++){ acc[cm][qi][0]=0.f; acc[cm][qi][1]=0.f;
                                  acc[cm][qi][2]=0.f; acc[cm][qi][3]=0.f; }
    float l[2] = {0.f, 0.f};
    const f16* kb = Gkt + (size_t)b*NHW*NC + c0;
    const f16* vb = Gv + ((size_t)b*NC + c0)*NHW;

    for (int j0 = 0; j0 < NHW; j0 += 64) {
        // ---- scores (A=K from global, B=q~): D[j=jm*16+quad*4+r][q=qi*16+l15] ----
#pragma unroll
        for (int jm = 0; jm < 4; ++jm) {
            const f16* kr = kb + (size_t)(j0 + jm*16 + l15)*NC + quad*8;
            H8 ka0, ka1;
            ka0.u4 = *(const uint4*)kr;
            ka1.u4 = *(const uint4*)(kr + 32);
            floatx4 s0 = {0.f,0.f,0.f,0.f}, s1 = {0.f,0.f,0.f,0.f};
            s0 = __builtin_amdgcn_mfma_f32_16x16x32_f16(ka0.h8, qa[0][0].h8, s0, 0, 0, 0);
            s0 = __builtin_amdgcn_mfma_f32_16x16x32_f16(ka1.h8, qa[0][1].h8, s0, 0, 0, 0);
            s1 = __builtin_amdgcn_mfma_f32_16x16x32_f16(ka0.h8, qa[1][0].h8, s1, 0, 0, 0);
            s1 = __builtin_amdgcn_mfma_f32_16x16x32_f16(ka1.h8, qa[1][1].h8, s1, 0, 0, 0);
            float4 mj4 = *(const float4*)(mi + j0 + jm*16 + quad*4);
            float mj[4] = {mj4.x, mj4.y, mj4.z, mj4.w};
            float p0[4], p1[4];
#pragma unroll
            for (int r = 0; r < 4; ++r) {
                float e0 = __expf(s0[r]*(mj[r]*QSCI)); l[0] += e0; p0[r] = e0*mj[r];
                float e1 = __expf(s1[r]*(mj[r]*QSCI)); l[1] += e1; p1[r] = e1*mj[r];
            }
            H4 k0, k1;
            k0.h2[0] = __floats2half2_rn(p0[0], p0[1]);
            k0.h2[1] = __floats2half2_rn(p0[2], p0[3]);
            k1.h2[0] = __floats2half2_rn(p1[0], p1[1]);
            k1.h2[1] = __floats2half2_rn(p1[2], p1[3]);
            *(uint2*)&ph[(size_t)l15*72      + jm*16 + quad*4] = k0.u2;
            *(uint2*)&ph[(size_t)(16+l15)*72 + jm*16 + quad*4] = k1.u2;
        }
        // ---- PV (A=V from global, B=P' from own LDS; same-wave, no barrier) ----
        H8 pb[2][2];
        pb[0][0].u4 = *(const uint4*)&ph[(size_t)l15*72      + quad*8];
        pb[0][1].u4 = *(const uint4*)&ph[(size_t)l15*72      + 32 + quad*8];
        pb[1][0].u4 = *(const uint4*)&ph[(size_t)(16+l15)*72 + quad*8];
        pb[1][1].u4 = *(const uint4*)&ph[(size_t)(16+l15)*72 + 32 + quad*8];
#pragma unroll
        for (int cm = 0; cm < 4; ++cm) {
            const f16* vr = vb + (size_t)(cm*16 + l15)*NHW + j0 + quad*8;
            H8 va0, va1;
            va0.u4 = *(const uint4*)vr;
            va1.u4 = *(const uint4*)(vr + 32);
            acc[cm][0] = __builtin_amdgcn_mfma_f32_16x16x32_f16(va0.h8, pb[0][0].h8, acc[cm][0], 0, 0, 0);
            acc[cm][0] = __builtin_amdgcn_mfma_f32_16x16x32_f16(va1.h8, pb[0][1].h8, acc[cm][0], 0, 0, 0);
            acc[cm][1] = __builtin_amdgcn_mfma_f32_16x16x32_f16(va0.h8, pb[1][0].h8, acc[cm][1], 0, 0, 0);
            acc[cm][1] = __builtin_amdgcn_mfma_f32_16x16x32_f16(va1.h8, pb[1][1].h8, acc[cm][1], 0, 0, 0);
        }
    }

    // ---- f = m_q / l  (reduce l over quad lanes: bits 4,5) ----
    float f[2];
#pragma unroll
    for (int qi = 0; qi < 2; ++qi) {
        float lv = l[qi];
        lv += __shfl_xor(lv, 16, 64);
        lv += __shfl_xor(lv, 32, 64);
        f[qi] = mqf[qi] / lv;
    }
    // ---- cross-instance sum: waves 0-3 write 4 bufs, waves 4-7 add, then store ----
    __syncthreads();                    // all PV LDS reads done before overlay
    if (w < 4) {
        float* rb = (float*)(lds + w*9216);
#pragma unroll
        for (int cm = 0; cm < 4; ++cm)
#pragma unroll
            for (int qi = 0; qi < 2; ++qi)
#pragma unroll
                for (int r = 0; r < 4; ++r)
                    rb[(cm*16 + quad*4 + r)*36 + qi*16 + l15] = f[qi]*acc[cm][qi][r];
    }
    __syncthreads();
    if (w >= 4) {
        float* rb = (float*)(lds + (w-4)*9216);
#pragma unroll
        for (int cm = 0; cm < 4; ++cm)
#pragma unroll
            for (int qi = 0; qi < 2; ++qi)
#pragma unroll
                for (int r = 0; r < 4; ++r)
                    rb[(cm*16 + quad*4 + r)*36 + qi*16 + l15] += f[qi]*acc[cm][qi][r];
    }
    __syncthreads();
    // ---- coalesced store + bv (sum_i mask_i = 1) ----
    int cc2 = tid >> 3, qg = (tid & 7)*4;
    float bvv = bv[c0 + cc2];
    float4 sum = {bvv, bvv, bvv, bvv};
#pragma unroll
    for (int buf = 0; buf < 4; ++buf) {
        float4 v = *(const float4*)(lds + (size_t)buf*9216 + (size_t)(cc2*36 + qg)*4);
        sum.x += v.x; sum.y += v.y; sum.z += v.z; sum.w += v.w;
    }
    *(float4*)(out + ((size_t)(b*NC + c0 + cc2))*NHW + qt0 + qg) = sum;
}

extern "C" void kernel_launch(void* const* d_in, const int* in_sizes, int n_in,
                              void* d_out, int out_size, void* d_ws, size_t ws_size,
                              hipStream_t stream)
{
    const float* x      = (const float*)d_in[0];
    const float* w_inst = (const float*)d_in[1];
    const float* b_inst = (const float*)d_in[2];
    const float* wq = (const float*)d_in[3];
    const float* bq = (const float*)d_in[4];
    const float* wk = (const float*)d_in[5];
    const float* bk = (const float*)d_in[6];
    const float* wv = (const float*)d_in[7];
    const float* bv = (const float*)d_in[8];
    float* out = (float*)d_out;

    float* masks   = (float*)d_ws;                        // 8*8*1024 f32
    float* scale_q = masks + (size_t)NI*NB*NHW;           // 8*8*256
    float* scale_k = scale_q + (size_t)NI*NB*NC;
    f16*   Gqt     = (f16*)(scale_k + (size_t)NI*NB*NC);  // [b][n][c] f16
    f16*   Gkt     = Gqt + (size_t)NB*NHW*NC;             // [b][n][c] f16
    f16*   Gv      = Gkt + (size_t)NB*NHW*NC;             // [b][c][n] f16
    float* part_m  = (float*)(Gv + (size_t)NB*NC*NHW);    // 8*8*8*1024
    float* part_nq = part_m + (size_t)8*NI*NB*NHW;        // 32*8*8*256
    float* part_nk = part_nq + (size_t)32*NI*NB*NC;

    k_mask_part<<<dim3(4, NB, 8), 256, 0, stream>>>(x, w_inst, part_m);
    k_mask_comb<<<dim3(4, NB), 256, 0, stream>>>(part_m, b_inst, masks);
    k_gemm1<<<dim3(8, 4, 24), 256, 0, stream>>>(x, wq, wk, wv, Gqt, Gkt, Gv);
    k_norm_part<<<dim3(32, NB), 256, 0, stream>>>(Gqt, Gkt, masks, bq, bk, part_nq, part_nk);
    k_norm_fin<<<dim3(NB, NI), 256, 0, stream>>>(part_nq, part_nk, scale_q, scale_k);
    k_attn5<<<dim3(1024), 512, 0, stream>>>(Gqt, Gkt, Gv, masks, bq, bv,
                                            scale_q, scale_k, out);
}

// Round 8
// 241.026 us; speedup vs baseline: 1.7718x; 1.7718x over previous
//
#include <hip/hip_runtime.h>
#include <hip/hip_fp16.h>

#define NB 8
#define NC 256
#define NHW 1024
#define NI 8
#define NH 4
#define HD 64
#define EPS 1e-12f
#define QSC  64.0f
#define QSCI 0.015625f

typedef _Float16 f16;
typedef __attribute__((ext_vector_type(8))) _Float16 half8;
typedef __attribute__((ext_vector_type(4))) float floatx4;

union H8 { half8 h8; __half2 h2[4]; uint4 u4; f16 e[8]; };
union H4 { uint2 u2; __half2 h2[2]; f16 e[4]; };

// ---------------- K1a: mask logit partials over 32-c chunks + xt emit ----------------
// grid (4 nt, 8 b, 8 cc), block 256. Also writes xt[b][n][c] f16 (x read anyway).
__global__ __launch_bounds__(256) void k_mask_part(
    const float* __restrict__ x, const float* __restrict__ w_inst,
    float* __restrict__ part_m, f16* __restrict__ xt)
{
    __shared__ float w_s[NI][32];
    __shared__ __align__(16) f16 xls[32][264];
    int nt = blockIdx.x, b = blockIdx.y, cc = blockIdx.z;
    int tid = threadIdx.x;
    w_s[tid >> 5][tid & 31] = w_inst[(tid >> 5)*NC + cc*32 + (tid & 31)];
    __syncthreads();
    int n = nt*256 + tid;
    const float* xp = x + ((size_t)(b*NC + cc*32))*NHW + n;
    float acc[NI] = {};
    for (int c = 0; c < 32; ++c) {
        float xv = xp[(size_t)c*NHW];
        xls[c][tid] = (f16)xv;
#pragma unroll
        for (int i = 0; i < NI; ++i) acc[i] = fmaf(w_s[i][c], xv, acc[i]);
    }
#pragma unroll
    for (int i = 0; i < NI; ++i)
        part_m[((size_t)(cc*NI + i)*NB + b)*NHW + n] = acc[i];
    __syncthreads();
    // transpose out: xt[b][nt*256 + r][cc*32 + c8..c8+7]
#pragma unroll
    for (int it = 0; it < 4; ++it) {
        int r = (tid >> 2) + it*64;
        int c8 = (tid & 3)*8;
        H8 v;
#pragma unroll
        for (int i = 0; i < 8; ++i) v.e[i] = xls[c8 + i][r];
        *(uint4*)(xt + ((size_t)(b*NHW + nt*256 + r))*NC + cc*32 + c8) = v.u4;
    }
}

// ---------------- K1b: combine + softmax over instances ----------------
__global__ __launch_bounds__(256) void k_mask_comb(
    const float* __restrict__ part_m, const float* __restrict__ b_inst,
    float* __restrict__ masks)
{
    int nt = blockIdx.x, b = blockIdx.y;
    int n = nt*256 + threadIdx.x;
    float a[NI];
#pragma unroll
    for (int i = 0; i < NI; ++i) {
        float s = b_inst[i];
#pragma unroll
        for (int cc = 0; cc < 8; ++cc)
            s += part_m[((size_t)(cc*NI + i)*NB + b)*NHW + n];
        a[i] = s;
    }
    float m = a[0];
#pragma unroll
    for (int i = 1; i < NI; ++i) m = fmaxf(m, a[i]);
    float ssum = 0.f;
#pragma unroll
    for (int i = 0; i < NI; ++i) { a[i] = __expf(a[i]-m); ssum += a[i]; }
    float inv = 1.0f/ssum;
#pragma unroll
    for (int i = 0; i < NI; ++i) masks[((size_t)i*NB + b)*NHW + n] = a[i]*inv;
}

// ---------------- K1c: W -> f16 cast ([3][256][256]) ----------------
__global__ __launch_bounds__(256) void k_wcast(
    const float* __restrict__ wq, const float* __restrict__ wk, const float* __restrict__ wv,
    f16* __restrict__ w16)
{
    int m = blockIdx.y;
    const float* src = (m == 0) ? wq : (m == 1) ? wk : wv;
    int e0 = (blockIdx.x*256 + threadIdx.x)*8;
    float4 a = *(const float4*)(src + e0);
    float4 c = *(const float4*)(src + e0 + 4);
    H8 h;
    h.h2[0] = __floats2half2_rn(a.x, a.y);
    h.h2[1] = __floats2half2_rn(a.z, a.w);
    h.h2[2] = __floats2half2_rn(c.x, c.y);
    h.h2[3] = __floats2half2_rn(c.z, c.w);
    *(uint4*)(w16 + (size_t)m*NC*NC + e0) = h.u4;
}

// ---------------- K2: MFMA f16 GEMM G = W*x (768 blocks) ----------------
// grid (8 nt, 4 ot, m*8+b). Double-buffered LDS staging; LDS-transpose epilogue.
__global__ __launch_bounds__(256) void k_gemm_mfma(
    const f16* __restrict__ xt, const f16* __restrict__ w16,
    f16* __restrict__ Gqt, f16* __restrict__ Gkt, f16* __restrict__ Gv)
{
    __shared__ __align__(16) char glds[30720];   // wt 2x64x40 f16 | xt 2x128x40 f16; epilogue overlay
    int tid = threadIdx.x;
    int nt = blockIdx.x, ot = blockIdx.y;
    int m = blockIdx.z >> 3, b = blockIdx.z & 7;
    int o0 = ot*64;
    int w = tid >> 6, lane = tid & 63, quad = lane >> 4, l15 = lane & 15;
    const f16* wm = w16 + (size_t)m*NC*NC;
    const f16* xb = xt + (size_t)b*NHW*NC + (size_t)nt*128*NC;
    f16* wt0 = (f16*)glds;                       // [2][64][40]
    f16* xt0 = (f16*)(glds + 10240);             // [2][128][40]
    int srow = tid >> 2, scol = (tid & 3)*8;

    floatx4 acc[2][4];   // [nm][om]
#pragma unroll
    for (int nm=0;nm<2;nm++)
#pragma unroll
        for (int om=0;om<4;om++){ acc[nm][om][0]=0.f; acc[nm][om][1]=0.f;
                                  acc[nm][om][2]=0.f; acc[nm][om][3]=0.f; }
    // stage k=0 into buf 0
    *(uint4*)&wt0[(0*64 + srow)*40 + scol]      = *(const uint4*)(wm + (size_t)(o0+srow)*NC + scol);
    *(uint4*)&xt0[(0*128 + srow)*40 + scol]     = *(const uint4*)(xb + (size_t)srow*NC + scol);
    *(uint4*)&xt0[(0*128 + 64+srow)*40 + scol]  = *(const uint4*)(xb + (size_t)(64+srow)*NC + scol);

    for (int k = 0; k < 8; ++k) {
        int p = k & 1;
        __syncthreads();
        if (k < 7) {
            int q = 1 - p, kc = (k+1)*32;
            *(uint4*)&wt0[(q*64 + srow)*40 + scol]     = *(const uint4*)(wm + (size_t)(o0+srow)*NC + kc + scol);
            *(uint4*)&xt0[(q*128 + srow)*40 + scol]    = *(const uint4*)(xb + (size_t)srow*NC + kc + scol);
            *(uint4*)&xt0[(q*128 + 64+srow)*40 + scol] = *(const uint4*)(xb + (size_t)(64+srow)*NC + kc + scol);
        }
        H8 wa[4], xa[2];
#pragma unroll
        for (int om = 0; om < 4; ++om)
            wa[om].u4 = *(const uint4*)&wt0[(p*64 + om*16 + l15)*40 + quad*8];
#pragma unroll
        for (int nm = 0; nm < 2; ++nm)
            xa[nm].u4 = *(const uint4*)&xt0[(p*128 + w*32 + nm*16 + l15)*40 + quad*8];
#pragma unroll
        for (int nm = 0; nm < 2; ++nm)
#pragma unroll
            for (int om = 0; om < 4; ++om)
                acc[nm][om] = __builtin_amdgcn_mfma_f32_16x16x32_f16(wa[om].h8, xa[nm].h8, acc[nm][om], 0, 0, 0);
    }
    __syncthreads();
    if (m < 2) {   // transposed store: lds_t [128 n][72 o]
        f16* lt = (f16*)glds;
#pragma unroll
        for (int nm = 0; nm < 2; ++nm)
#pragma unroll
            for (int om = 0; om < 4; ++om) {
                H4 pk;
#pragma unroll
                for (int r = 0; r < 4; ++r) pk.e[r] = (f16)acc[nm][om][r];
                *(uint2*)&lt[(size_t)(w*32 + nm*16 + l15)*72 + om*16 + quad*4] = pk.u2;
            }
        __syncthreads();
        f16* dst = (m == 0) ? Gqt : Gkt;
#pragma unroll
        for (int it = 0; it < 4; ++it) {
            int row = (tid >> 3) + it*32;
            int c8 = (tid & 7)*8;
            uint4 v = *(const uint4*)&lt[(size_t)row*72 + c8];
            *(uint4*)(dst + ((size_t)(b*NHW + nt*128 + row))*NC + o0 + c8) = v;
        }
    } else {       // natural store: lds_v [64 o][136 n]
        f16* lv = (f16*)glds;
#pragma unroll
        for (int nm = 0; nm < 2; ++nm)
#pragma unroll
            for (int om = 0; om < 4; ++om)
#pragma unroll
                for (int r = 0; r < 4; ++r)
                    lv[(size_t)(om*16 + quad*4 + r)*136 + w*32 + nm*16 + l15] = (f16)acc[nm][om][r];
        __syncthreads();
#pragma unroll
        for (int it = 0; it < 4; ++it) {
            int row = (tid >> 4) + it*16;
            int n8 = (tid & 15)*8;
            uint4 v = *(const uint4*)&lv[(size_t)row*136 + n8];
            *(uint4*)(Gv + ((size_t)(b*NC + o0 + row))*NHW + nt*128 + n8) = v;
        }
    }
}

// ---------------- K3a: norm partials over 32-n chunks (256 blocks) ----------------
__global__ __launch_bounds__(256) void k_norm_part(
    const f16* __restrict__ Gqt, const f16* __restrict__ Gkt,
    const float* __restrict__ masks,
    const float* __restrict__ bq, const float* __restrict__ bk,
    float* __restrict__ part_nq, float* __restrict__ part_nk)
{
    __shared__ float m_s[NI][32];
    int nc = blockIdx.x, b = blockIdx.y;
    int c = threadIdx.x;
    int n0 = nc*32;
    m_s[c >> 5][c & 31] = masks[((size_t)(c >> 5)*NB + b)*NHW + n0 + (c & 31)];
    __syncthreads();
    float bqv = bq[c], bkv = bk[c];
    const f16* gq = Gqt + ((size_t)b*NHW + n0)*NC + c;
    const f16* gk = Gkt + ((size_t)b*NHW + n0)*NC + c;
    float aq[NI] = {}, ak[NI] = {};
    for (int t = 0; t < 32; ++t) {
        float g1 = (float)gq[(size_t)t*NC];
        float g2 = (float)gk[(size_t)t*NC];
#pragma unroll
        for (int i = 0; i < NI; ++i) {
            float mm = m_s[i][t];
            float e = fmaf(mm, g1, bqv); aq[i] = fmaf(e, e, aq[i]);
            e = fmaf(mm, g2, bkv);       ak[i] = fmaf(e, e, ak[i]);
        }
    }
#pragma unroll
    for (int i = 0; i < NI; ++i) {
        part_nq[((size_t)(nc*NI + i)*NB + b)*NC + c] = aq[i];
        part_nk[((size_t)(nc*NI + i)*NB + b)*NC + c] = ak[i];
    }
}

// ---------------- K3b: finalize scales ----------------
__global__ __launch_bounds__(256) void k_norm_fin(
    const float* __restrict__ part_nq, const float* __restrict__ part_nk,
    float* __restrict__ scale_q, float* __restrict__ scale_k)
{
    int b = blockIdx.x, i = blockIdx.y, c = threadIdx.x;
    float sq = 0.f, sk = 0.f;
#pragma unroll
    for (int nc = 0; nc < 32; ++nc) {
        sq += part_nq[((size_t)(nc*NI + i)*NB + b)*NC + c];
        sk += part_nk[((size_t)(nc*NI + i)*NB + b)*NC + c];
    }
    scale_q[((size_t)i*NB + b)*NC + c] = 0.125f / fmaxf(sqrtf(sq), EPS);
    scale_k[((size_t)i*NB + b)*NC + c] = 1.0f   / fmaxf(sqrtf(sk), EPS);
}

// ---------------- K4: fused attention v6 — round-6 structure + frag hoisting ----------------
// grid 1024 (b=bid&7 XCD pin), block 256 = 4 waves, wave w = instances {2w,2w+1}.
// ka/va hoisted per tile (regs), pb per instance: 24 ds_read_b128/tile/wave (was 64).
// Cross-instance sum: 2-phase tree overlaid on ph_s.
__global__ __launch_bounds__(256,2) void k_attn6(
    const f16* __restrict__ Gqt, const f16* __restrict__ Gkt, const f16* __restrict__ Gv,
    const float* __restrict__ masks,
    const float* __restrict__ bq, const float* __restrict__ bv,
    const float* __restrict__ scale_q, const float* __restrict__ scale_k,
    float* __restrict__ out)
{
    __shared__ __align__(16) f16 kh_s[64][72];
    __shared__ __align__(16) f16 vh_s[64][72];
    __shared__ __align__(16) f16 ph_s[4][32][72];   // reused as 2 fp32 reduce bufs at the end
    __shared__ __align__(16) float mi_s[NI][64];

    int tid = threadIdx.x, bid = blockIdx.x;
    int b = bid & 7, qt = (bid >> 3) & 31, h = bid >> 8;
    int qt0 = qt*32, c0 = h*HD;
    int w = tid >> 6, lane = tid & 63, quad = lane >> 4, l15 = lane & 15;
    int i0 = 2*w;
    f16* ph = &ph_s[w][0][0];

    // ---- hoisted raw Gq B-frags ----
    H8 graw[2][2];
    const f16* gqp = Gqt + ((size_t)b*NHW + qt0)*NC + c0;
#pragma unroll
    for (int qi = 0; qi < 2; ++qi)
#pragma unroll
        for (int ks = 0; ks < 2; ++ks)
            graw[qi][ks].u4 = *(const uint4*)(gqp + (size_t)(qi*16 + l15)*NC + ks*32 + quad*8);

    float mqf[2][2];
#pragma unroll
    for (int ii = 0; ii < 2; ++ii)
#pragma unroll
        for (int qi = 0; qi < 2; ++qi)
            mqf[ii][qi] = masks[((size_t)(i0+ii)*NB + b)*NHW + qt0 + qi*16 + l15];

    // ---- hoisted q~ frags (mask, bias, scales, x64 folded) ----
    H8 qa[2][2][2];   // [ii][qi][ks]
#pragma unroll
    for (int ks = 0; ks < 2; ++ks) {
        int cb = c0 + ks*32 + quad*8;
        float4 bq0 = *(const float4*)(bq + cb);
        float4 bq1 = *(const float4*)(bq + cb + 4);
#pragma unroll
        for (int ii = 0; ii < 2; ++ii) {
            int inst = i0 + ii;
            const float* sqg = scale_q + ((size_t)inst*NB + b)*NC;
            const float* skg = scale_k + ((size_t)inst*NB + b)*NC;
            float4 s0 = *(const float4*)(sqg + cb);
            float4 s1 = *(const float4*)(sqg + cb + 4);
            float4 t0 = *(const float4*)(skg + cb);
            float4 t1 = *(const float4*)(skg + cb + 4);
            float ss[8] = {s0.x*t0.x*QSC, s0.y*t0.y*QSC, s0.z*t0.z*QSC, s0.w*t0.w*QSC,
                           s1.x*t1.x*QSC, s1.y*t1.y*QSC, s1.z*t1.z*QSC, s1.w*t1.w*QSC};
            float bb[8] = {bq0.x*ss[0], bq0.y*ss[1], bq0.z*ss[2], bq0.w*ss[3],
                           bq1.x*ss[4], bq1.y*ss[5], bq1.z*ss[6], bq1.w*ss[7]};
            __half2 sh[4], bh[4];
#pragma unroll
            for (int t = 0; t < 4; ++t) {
                sh[t] = __floats2half2_rn(ss[2*t], ss[2*t+1]);
                bh[t] = __floats2half2_rn(bb[2*t], bb[2*t+1]);
            }
#pragma unroll
            for (int qi = 0; qi < 2; ++qi) {
                __half2 mq2 = __float2half2_rn(mqf[ii][qi]);
#pragma unroll
                for (int t = 0; t < 4; ++t)
                    qa[ii][qi][ks].h2[t] = __hfma2(mq2, __hmul2(graw[qi][ks].h2[t], sh[t]), bh[t]);
            }
        }
    }

    floatx4 acc[2][4][2];   // [ii][cm][qi]
#pragma unroll
    for (int ii=0;ii<2;ii++)
#pragma unroll
        for (int cm=0;cm<4;cm++)
#pragma unroll
            for (int qi=0;qi<2;qi++) { acc[ii][cm][qi][0]=0.f; acc[ii][cm][qi][1]=0.f;
                                       acc[ii][cm][qi][2]=0.f; acc[ii][cm][qi][3]=0.f; }
    float l[2][2] = {};

    for (int j0 = 0; j0 < NHW; j0 += 64) {
        __syncthreads();
#pragma unroll
        for (int t = 0; t < 2; ++t) {
            int chk = tid + t*256;
            int jr = chk >> 3, cc = chk & 7;
            *(uint4*)&kh_s[jr][cc*8] = *(const uint4*)(Gkt + ((size_t)b*NHW + j0 + jr)*NC + c0 + cc*8);
            *(uint4*)&vh_s[jr][cc*8] = *(const uint4*)(Gv + ((size_t)b*NC + c0 + jr)*NHW + j0 + cc*8);
        }
        {
            int i = tid >> 5, jj = (tid & 31)*2;
            *(float2*)&mi_s[i][jj] = *(const float2*)(masks + ((size_t)i*NB + b)*NHW + j0 + jj);
        }
        __syncthreads();
        // ---- hoist all K/V A-frags for this tile into registers ----
        H8 ka[4][2], va[4][2];
#pragma unroll
        for (int jm = 0; jm < 4; ++jm)
#pragma unroll
            for (int ks = 0; ks < 2; ++ks) {
                ka[jm][ks].u4 = *(const uint4*)&kh_s[jm*16 + l15][ks*32 + quad*8];
                va[jm][ks].u4 = *(const uint4*)&vh_s[jm*16 + l15][ks*32 + quad*8];
            }
#pragma unroll
        for (int ii = 0; ii < 2; ++ii) {
            int inst = i0 + ii;
#pragma unroll
            for (int jm = 0; jm < 4; ++jm) {
                floatx4 s0 = {0.f,0.f,0.f,0.f}, s1 = {0.f,0.f,0.f,0.f};
#pragma unroll
                for (int ks = 0; ks < 2; ++ks) {
                    s0 = __builtin_amdgcn_mfma_f32_16x16x32_f16(ka[jm][ks].h8, qa[ii][0][ks].h8, s0, 0, 0, 0);
                    s1 = __builtin_amdgcn_mfma_f32_16x16x32_f16(ka[jm][ks].h8, qa[ii][1][ks].h8, s1, 0, 0, 0);
                }
                float4 mj4 = *(const float4*)&mi_s[inst][jm*16 + quad*4];
                float mj[4] = {mj4.x, mj4.y, mj4.z, mj4.w};
                float p0[4], p1[4];
#pragma unroll
                for (int r = 0; r < 4; ++r) {
                    float e0 = __expf(s0[r]*(mj[r]*QSCI)); l[ii][0] += e0; p0[r] = e0*mj[r];
                    float e1 = __expf(s1[r]*(mj[r]*QSCI)); l[ii][1] += e1; p1[r] = e1*mj[r];
                }
                H4 pk0, pk1;
                pk0.h2[0] = __floats2half2_rn(p0[0], p0[1]);
                pk0.h2[1] = __floats2half2_rn(p0[2], p0[3]);
                pk1.h2[0] = __floats2half2_rn(p1[0], p1[1]);
                pk1.h2[1] = __floats2half2_rn(p1[2], p1[3]);
                *(uint2*)&ph[(size_t)l15*72      + jm*16 + quad*4] = pk0.u2;
                *(uint2*)&ph[(size_t)(16+l15)*72 + jm*16 + quad*4] = pk1.u2;
            }
            // pb hoist (same-wave LDS round trip; in-order DS pipe)
            H8 pb[2][2];
#pragma unroll
            for (int qi = 0; qi < 2; ++qi)
#pragma unroll
                for (int ks = 0; ks < 2; ++ks)
                    pb[qi][ks].u4 = *(const uint4*)&ph[(size_t)(qi*16 + l15)*72 + ks*32 + quad*8];
#pragma unroll
            for (int cm = 0; cm < 4; ++cm)
#pragma unroll
                for (int ks = 0; ks < 2; ++ks) {
                    acc[ii][cm][0] = __builtin_amdgcn_mfma_f32_16x16x32_f16(va[cm][ks].h8, pb[0][ks].h8, acc[ii][cm][0], 0, 0, 0);
                    acc[ii][cm][1] = __builtin_amdgcn_mfma_f32_16x16x32_f16(va[cm][ks].h8, pb[1][ks].h8, acc[ii][cm][1], 0, 0, 0);
                }
        }
    }

    // ---- f = m_q/l (reduce over quads: lane bits 4,5) ----
    float f[2][2];
#pragma unroll
    for (int ii = 0; ii < 2; ++ii)
#pragma unroll
        for (int qi = 0; qi < 2; ++qi) {
            float lv = l[ii][qi];
            lv += __shfl_xor(lv, 16, 64);
            lv += __shfl_xor(lv, 32, 64);
            f[ii][qi] = mqf[ii][qi] / lv;
        }
    // ---- cross-instance 2-phase tree on ph_s overlay ----
    float* bufA = (float*)&ph_s[0][0][0];
    float* bufB = bufA + 2304;
    __syncthreads();
    if (w < 2) {
        float* rb = w ? bufB : bufA;
#pragma unroll
        for (int cm = 0; cm < 4; ++cm)
#pragma unroll
            for (int qi = 0; qi < 2; ++qi)
#pragma unroll
                for (int r = 0; r < 4; ++r)
                    rb[(cm*16 + quad*4 + r)*36 + qi*16 + l15] =
                        f[0][qi]*acc[0][cm][qi][r] + f[1][qi]*acc[1][cm][qi][r];
    }
    __syncthreads();
    if (w >= 2) {
        float* rb = (w == 3) ? bufB : bufA;
#pragma unroll
        for (int cm = 0; cm < 4; ++cm)
#pragma unroll
            for (int qi = 0; qi < 2; ++qi)
#pragma unroll
                for (int r = 0; r < 4; ++r)
                    rb[(cm*16 + quad*4 + r)*36 + qi*16 + l15] +=
                        f[0][qi]*acc[0][cm][qi][r] + f[1][qi]*acc[1][cm][qi][r];
    }
    __syncthreads();
    // ---- coalesced store + bv (sum_i mask_i = 1) ----
    int cc2 = tid >> 2, qg = (tid & 3)*8;
    float bvv = bv[c0 + cc2];
    float* op = out + ((size_t)(b*NC + c0 + cc2))*NHW + qt0;
#pragma unroll
    for (int t = 0; t < 2; ++t) {
        float4 va4 = *(const float4*)&bufA[cc2*36 + qg + t*4];
        float4 vb4 = *(const float4*)&bufB[cc2*36 + qg + t*4];
        float4 v;
        v.x = va4.x + vb4.x + bvv; v.y = va4.y + vb4.y + bvv;
        v.z = va4.z + vb4.z + bvv; v.w = va4.w + vb4.w + bvv;
        *(float4*)(op + qg + t*4) = v;
    }
}

extern "C" void kernel_launch(void* const* d_in, const int* in_sizes, int n_in,
                              void* d_out, int out_size, void* d_ws, size_t ws_size,
                              hipStream_t stream)
{
    const float* x      = (const float*)d_in[0];
    const float* w_inst = (const float*)d_in[1];
    const float* b_inst = (const float*)d_in[2];
    const float* wq = (const float*)d_in[3];
    const float* bq = (const float*)d_in[4];
    const float* wk = (const float*)d_in[5];
    const float* bk = (const float*)d_in[6];
    const float* wv = (const float*)d_in[7];
    const float* bv = (const float*)d_in[8];
    float* out = (float*)d_out;

    float* masks   = (float*)d_ws;                        // 8*8*1024 f32
    float* scale_q = masks + (size_t)NI*NB*NHW;           // 8*8*256
    float* scale_k = scale_q + (size_t)NI*NB*NC;
    f16*   Gqt     = (f16*)(scale_k + (size_t)NI*NB*NC);  // [b][n][c] f16
    f16*   Gkt     = Gqt + (size_t)NB*NHW*NC;             // [b][n][c] f16
    f16*   Gv      = Gkt + (size_t)NB*NHW*NC;             // [b][c][n] f16
    f16*   xt      = Gv + (size_t)NB*NC*NHW;              // [b][n][c] f16
    f16*   w16     = xt + (size_t)NB*NHW*NC;              // [3][256][256] f16
    float* part_m  = (float*)(w16 + (size_t)3*NC*NC);     // 8*8*8*1024
    float* part_nq = part_m + (size_t)8*NI*NB*NHW;        // 32*8*8*256
    float* part_nk = part_nq + (size_t)32*NI*NB*NC;

    k_mask_part<<<dim3(4, NB, 8), 256, 0, stream>>>(x, w_inst, part_m, xt);
    k_wcast<<<dim3(32, 3), 256, 0, stream>>>(wq, wk, wv, w16);
    k_mask_comb<<<dim3(4, NB), 256, 0, stream>>>(part_m, b_inst, masks);
    k_gemm_mfma<<<dim3(8, 4, 24), 256, 0, stream>>>(xt, w16, Gqt, Gkt, Gv);
    k_norm_part<<<dim3(32, NB), 256, 0, stream>>>(Gqt, Gkt, masks, bq, bk, part_nq, part_nk);
    k_norm_fin<<<dim3(NB, NI), 256, 0, stream>>>(part_nq, part_nk, scale_q, scale_k);
    k_attn6<<<dim3(1024), 256, 0, stream>>>(Gqt, Gkt, Gv, masks, bq, bv,
                                            scale_q, scale_k, out);
}

// Round 10
// 230.079 us; speedup vs baseline: 1.8561x; 1.0476x over previous
//
#include <hip/hip_runtime.h>
#include <hip/hip_fp16.h>

#define NB 8
#define NC 256
#define NHW 1024
#define NI 8
#define NH 4
#define HD 64
#define EPS 1e-12f
#define QSC  64.0f
#define QSCI 0.015625f

typedef _Float16 f16;
typedef __attribute__((ext_vector_type(8))) _Float16 half8;
typedef __attribute__((ext_vector_type(4))) float floatx4;

union H8 { half8 h8; __half2 h2[4]; uint4 u4; f16 e[8]; };
union H4 { uint2 u2; __half2 h2[2]; f16 e[4]; };

__device__ __forceinline__ void gll16(const void* g, void* l) {
    __builtin_amdgcn_global_load_lds(
        (const __attribute__((address_space(1))) unsigned int*)g,
        (__attribute__((address_space(3))) unsigned int*)l, 16, 0, 0);
}

// ---------------- K1: mask logit partials over 32-c chunks + xt emit ----------------
__global__ __launch_bounds__(256) void k_mask_part(
    const float* __restrict__ x, const float* __restrict__ w_inst,
    float* __restrict__ part_m, f16* __restrict__ xt)
{
    __shared__ float w_s[NI][32];
    __shared__ __align__(16) f16 xls[32][264];
    int nt = blockIdx.x, b = blockIdx.y, cc = blockIdx.z;
    int tid = threadIdx.x;
    w_s[tid >> 5][tid & 31] = w_inst[(tid >> 5)*NC + cc*32 + (tid & 31)];
    __syncthreads();
    int n = nt*256 + tid;
    const float* xp = x + ((size_t)(b*NC + cc*32))*NHW + n;
    float acc[NI] = {};
    for (int c = 0; c < 32; ++c) {
        float xv = xp[(size_t)c*NHW];
        xls[c][tid] = (f16)xv;
#pragma unroll
        for (int i = 0; i < NI; ++i) acc[i] = fmaf(w_s[i][c], xv, acc[i]);
    }
#pragma unroll
    for (int i = 0; i < NI; ++i)
        part_m[((size_t)(cc*NI + i)*NB + b)*NHW + n] = acc[i];
    __syncthreads();
#pragma unroll
    for (int it = 0; it < 4; ++it) {
        int r = (tid >> 2) + it*64;
        int c8 = (tid & 3)*8;
        H8 v;
#pragma unroll
        for (int i = 0; i < 8; ++i) v.e[i] = xls[c8 + i][r];
        *(uint4*)(xt + ((size_t)(b*NHW + nt*256 + r))*NC + cc*32 + c8) = v.u4;
    }
}

// ---------------- K2: MFMA f16 GEMM G = W*x, W cast inline (768 blocks) ----------------
__global__ __launch_bounds__(256) void k_gemm_mfma(
    const f16* __restrict__ xt,
    const float* __restrict__ wq, const float* __restrict__ wk, const float* __restrict__ wv,
    f16* __restrict__ Gqt, f16* __restrict__ Gkt, f16* __restrict__ Gv)
{
    __shared__ __align__(16) char glds[30720];
    int tid = threadIdx.x;
    int nt = blockIdx.x, ot = blockIdx.y;
    int m = blockIdx.z >> 3, b = blockIdx.z & 7;
    const float* wsel = (m == 0) ? wq : (m == 1) ? wk : wv;
    int o0 = ot*64;
    int w = tid >> 6, lane = tid & 63, quad = lane >> 4, l15 = lane & 15;
    const f16* xb = xt + (size_t)b*NHW*NC + (size_t)nt*128*NC;
    f16* wt0 = (f16*)glds;                       // [2][64][40]
    f16* xt0 = (f16*)(glds + 10240);             // [2][128][40]
    int srow = tid >> 2, scol = (tid & 3)*8;

    floatx4 acc[2][4];
#pragma unroll
    for (int nm=0;nm<2;nm++)
#pragma unroll
        for (int om=0;om<4;om++){ acc[nm][om][0]=0.f; acc[nm][om][1]=0.f;
                                  acc[nm][om][2]=0.f; acc[nm][om][3]=0.f; }
    {   // stage k=0 into buf 0 (cast W fp32->f16 inline)
        float4 a4 = *(const float4*)(wsel + (size_t)(o0+srow)*NC + scol);
        float4 b4 = *(const float4*)(wsel + (size_t)(o0+srow)*NC + scol + 4);
        H8 hw;
        hw.h2[0] = __floats2half2_rn(a4.x, a4.y); hw.h2[1] = __floats2half2_rn(a4.z, a4.w);
        hw.h2[2] = __floats2half2_rn(b4.x, b4.y); hw.h2[3] = __floats2half2_rn(b4.z, b4.w);
        *(uint4*)&wt0[(0*64 + srow)*40 + scol] = hw.u4;
        *(uint4*)&xt0[(0*128 + srow)*40 + scol]    = *(const uint4*)(xb + (size_t)srow*NC + scol);
        *(uint4*)&xt0[(0*128 + 64+srow)*40 + scol] = *(const uint4*)(xb + (size_t)(64+srow)*NC + scol);
    }
    for (int k = 0; k < 8; ++k) {
        int p = k & 1;
        __syncthreads();
        if (k < 7) {
            int q = 1 - p, kc = (k+1)*32;
            float4 a4 = *(const float4*)(wsel + (size_t)(o0+srow)*NC + kc + scol);
            float4 b4 = *(const float4*)(wsel + (size_t)(o0+srow)*NC + kc + scol + 4);
            H8 hw;
            hw.h2[0] = __floats2half2_rn(a4.x, a4.y); hw.h2[1] = __floats2half2_rn(a4.z, a4.w);
            hw.h2[2] = __floats2half2_rn(b4.x, b4.y); hw.h2[3] = __floats2half2_rn(b4.z, b4.w);
            *(uint4*)&wt0[(q*64 + srow)*40 + scol] = hw.u4;
            *(uint4*)&xt0[(q*128 + srow)*40 + scol]    = *(const uint4*)(xb + (size_t)srow*NC + kc + scol);
            *(uint4*)&xt0[(q*128 + 64+srow)*40 + scol] = *(const uint4*)(xb + (size_t)(64+srow)*NC + kc + scol);
        }
        H8 wa[4], xa[2];
#pragma unroll
        for (int om = 0; om < 4; ++om)
            wa[om].u4 = *(const uint4*)&wt0[(p*64 + om*16 + l15)*40 + quad*8];
#pragma unroll
        for (int nm = 0; nm < 2; ++nm)
            xa[nm].u4 = *(const uint4*)&xt0[(p*128 + w*32 + nm*16 + l15)*40 + quad*8];
#pragma unroll
        for (int nm = 0; nm < 2; ++nm)
#pragma unroll
            for (int om = 0; om < 4; ++om)
                acc[nm][om] = __builtin_amdgcn_mfma_f32_16x16x32_f16(wa[om].h8, xa[nm].h8, acc[nm][om], 0, 0, 0);
    }
    __syncthreads();
    if (m < 2) {
        f16* lt = (f16*)glds;   // [128][72]
#pragma unroll
        for (int nm = 0; nm < 2; ++nm)
#pragma unroll
            for (int om = 0; om < 4; ++om) {
                H4 pk;
#pragma unroll
                for (int r = 0; r < 4; ++r) pk.e[r] = (f16)acc[nm][om][r];
                *(uint2*)&lt[(size_t)(w*32 + nm*16 + l15)*72 + om*16 + quad*4] = pk.u2;
            }
        __syncthreads();
        f16* dst = (m == 0) ? Gqt : Gkt;
#pragma unroll
        for (int it = 0; it < 4; ++it) {
            int row = (tid >> 3) + it*32;
            int c8 = (tid & 7)*8;
            uint4 v = *(const uint4*)&lt[(size_t)row*72 + c8];
            *(uint4*)(dst + ((size_t)(b*NHW + nt*128 + row))*NC + o0 + c8) = v;
        }
    } else {
        f16* lv = (f16*)glds;   // [64][136]
#pragma unroll
        for (int nm = 0; nm < 2; ++nm)
#pragma unroll
            for (int om = 0; om < 4; ++om)
#pragma unroll
                for (int r = 0; r < 4; ++r)
                    lv[(size_t)(om*16 + quad*4 + r)*136 + w*32 + nm*16 + l15] = (f16)acc[nm][om][r];
        __syncthreads();
#pragma unroll
        for (int it = 0; it < 4; ++it) {
            int row = (tid >> 4) + it*16;
            int n8 = (tid & 15)*8;
            uint4 v = *(const uint4*)&lv[(size_t)row*136 + n8];
            *(uint4*)(Gv + ((size_t)(b*NC + o0 + row))*NHW + nt*128 + n8) = v;
        }
    }
}

// ---------------- K3: fused mask-softmax + norm partials (256 blocks) ----------------
__global__ __launch_bounds__(256) void k_norm_mask(
    const float* __restrict__ part_m, const float* __restrict__ b_inst,
    const f16* __restrict__ Gqt, const f16* __restrict__ Gkt,
    const float* __restrict__ bq, const float* __restrict__ bk,
    float* __restrict__ masks, float* __restrict__ part_nq, float* __restrict__ part_nk)
{
    __shared__ float lg[NI][32];
    __shared__ float m_s[NI][32];
    int nc = blockIdx.x, b = blockIdx.y;
    int tid = threadIdx.x;
    int n0 = nc*32;
    {
        int nl = tid & 31, i = tid >> 5;
        float s = b_inst[i];
#pragma unroll
        for (int cc = 0; cc < 8; ++cc)
            s += part_m[((size_t)(cc*NI + i)*NB + b)*NHW + n0 + nl];
        lg[i][nl] = s;
    }
    __syncthreads();
    {
        int nl = tid & 31, i = tid >> 5;
        float mx = lg[0][nl];
#pragma unroll
        for (int k = 1; k < NI; ++k) mx = fmaxf(mx, lg[k][nl]);
        float ssum = 0.f;
#pragma unroll
        for (int k = 0; k < NI; ++k) ssum += __expf(lg[k][nl] - mx);
        float mv = __expf(lg[i][nl] - mx) / ssum;
        m_s[i][nl] = mv;
        masks[((size_t)i*NB + b)*NHW + n0 + nl] = mv;
    }
    __syncthreads();
    int c = tid;
    float bqv = bq[c], bkv = bk[c];
    const f16* gq = Gqt + ((size_t)b*NHW + n0)*NC + c;
    const f16* gk = Gkt + ((size_t)b*NHW + n0)*NC + c;
    float aq[NI] = {}, ak[NI] = {};
    for (int t = 0; t < 32; ++t) {
        float g1 = (float)gq[(size_t)t*NC];
        float g2 = (float)gk[(size_t)t*NC];
#pragma unroll
        for (int i = 0; i < NI; ++i) {
            float mm = m_s[i][t];
            float e = fmaf(mm, g1, bqv); aq[i] = fmaf(e, e, aq[i]);
            e = fmaf(mm, g2, bkv);       ak[i] = fmaf(e, e, ak[i]);
        }
    }
#pragma unroll
    for (int i = 0; i < NI; ++i) {
        part_nq[((size_t)(nc*NI + i)*NB + b)*NC + c] = aq[i];
        part_nk[((size_t)(nc*NI + i)*NB + b)*NC + c] = ak[i];
    }
}

// ---------------- K3b: finalize scales ----------------
__global__ __launch_bounds__(256) void k_norm_fin(
    const float* __restrict__ part_nq, const float* __restrict__ part_nk,
    float* __restrict__ scale_q, float* __restrict__ scale_k)
{
    int b = blockIdx.x, i = blockIdx.y, c = threadIdx.x;
    float sq = 0.f, sk = 0.f;
#pragma unroll
    for (int nc = 0; nc < 32; ++nc) {
        sq += part_nq[((size_t)(nc*NI + i)*NB + b)*NC + c];
        sk += part_nk[((size_t)(nc*NI + i)*NB + b)*NC + c];
    }
    scale_q[((size_t)i*NB + b)*NC + c] = 0.125f / fmaxf(sqrtf(sq), EPS);
    scale_k[((size_t)i*NB + b)*NC + c] = 1.0f   / fmaxf(sqrtf(sk), EPS);
}

// ---------------- K4: attention v7b — async gll staging (stride bug fixed) ----------------
// grid 1024 (b=bid&7 XCD pin), block 256 = 4 waves, wave w = instances {2w,2w+1}.
// LDS map (BYTES): KH [2][32][64]f16 @0 (buf stride 2048 f16 = 4096B)
//                  VH [2][64][32]f16 @8192 (buf stride 2048 f16)
//                  MI [2][8][32]f32 @16384 (buf stride 256 f32)
//                  PH [4 waves][2 inst][32][40]f16 @18432
__global__ __launch_bounds__(256,2) void k_attn7(
    const f16* __restrict__ Gqt, const f16* __restrict__ Gkt, const f16* __restrict__ Gv,
    const float* __restrict__ masks,
    const float* __restrict__ bq, const float* __restrict__ bv,
    const float* __restrict__ scale_q, const float* __restrict__ scale_k,
    float* __restrict__ out)
{
    __shared__ __align__(16) char lds[38912];
    f16*   KH = (f16*)lds;
    f16*   VH = (f16*)(lds + 8192);
    float* MI = (float*)(lds + 16384);
    f16*   PH = (f16*)(lds + 18432);

    int tid = threadIdx.x, bid = blockIdx.x;
    int b = bid & 7, qt = (bid >> 3) & 31, h = bid >> 8;
    int qt0 = qt*32, c0 = h*HD;
    int w = tid >> 6, lane = tid & 63, quad = lane >> 4, l15 = lane & 15;
    int i0 = 2*w;

    // ---- hoisted raw Gq B-frags + per-instance q~ (mask/bias/scales, x64) ----
    H8 graw[2][2];
    const f16* gqp = Gqt + ((size_t)b*NHW + qt0)*NC + c0;
#pragma unroll
    for (int qi = 0; qi < 2; ++qi)
#pragma unroll
        for (int ks = 0; ks < 2; ++ks)
            graw[qi][ks].u4 = *(const uint4*)(gqp + (size_t)(qi*16 + l15)*NC + ks*32 + quad*8);
    float mqf[2][2];
#pragma unroll
    for (int ii = 0; ii < 2; ++ii)
#pragma unroll
        for (int qi = 0; qi < 2; ++qi)
            mqf[ii][qi] = masks[((size_t)(i0+ii)*NB + b)*NHW + qt0 + qi*16 + l15];
    H8 qa[2][2][2];
#pragma unroll
    for (int ks = 0; ks < 2; ++ks) {
        int cb = c0 + ks*32 + quad*8;
        float4 bq0 = *(const float4*)(bq + cb);
        float4 bq1 = *(const float4*)(bq + cb + 4);
#pragma unroll
        for (int ii = 0; ii < 2; ++ii) {
            int inst = i0 + ii;
            const float* sqg = scale_q + ((size_t)inst*NB + b)*NC;
            const float* skg = scale_k + ((size_t)inst*NB + b)*NC;
            float4 s0 = *(const float4*)(sqg + cb);
            float4 s1 = *(const float4*)(sqg + cb + 4);
            float4 t0 = *(const float4*)(skg + cb);
            float4 t1 = *(const float4*)(skg + cb + 4);
            float ss[8] = {s0.x*t0.x*QSC, s0.y*t0.y*QSC, s0.z*t0.z*QSC, s0.w*t0.w*QSC,
                           s1.x*t1.x*QSC, s1.y*t1.y*QSC, s1.z*t1.z*QSC, s1.w*t1.w*QSC};
            float bb[8] = {bq0.x*ss[0], bq0.y*ss[1], bq0.z*ss[2], bq0.w*ss[3],
                           bq1.x*ss[4], bq1.y*ss[5], bq1.z*ss[6], bq1.w*ss[7]};
            __half2 sh[4], bh[4];
#pragma unroll
            for (int t = 0; t < 4; ++t) {
                sh[t] = __floats2half2_rn(ss[2*t], ss[2*t+1]);
                bh[t] = __floats2half2_rn(bb[2*t], bb[2*t+1]);
            }
#pragma unroll
            for (int qi = 0; qi < 2; ++qi) {
                __half2 mq2 = __float2half2_rn(mqf[ii][qi]);
#pragma unroll
                for (int t = 0; t < 4; ++t)
                    qa[ii][qi][ks].h2[t] = __hfma2(mq2, __hmul2(graw[qi][ks].h2[t], sh[t]), bh[t]);
            }
        }
    }

    // ---- staging lane constants (XOR source-swizzle) ----
    int kjr = tid >> 3, kdc = (tid & 7) ^ (kjr & 7);           // kh: 32 rows x 8 chunks
    int vcr = tid >> 2, vdc = (tid & 3) ^ (vcr & 3);           // vh: 64 rows x 4 chunks
    const f16* kgb = Gkt + (size_t)b*NHW*NC + c0 + kdc*8;      // + (jn+kjr)*NC
    const f16* vgb = Gv + ((size_t)(b*NC + c0 + vcr))*NHW + vdc*8;
    const float* mgb = masks + ((size_t)(lane >> 3)*NB + b)*NHW + (lane & 7)*4;

    floatx4 acc[2][4][2];
#pragma unroll
    for (int ii=0;ii<2;ii++)
#pragma unroll
        for (int cm=0;cm<4;cm++)
#pragma unroll
            for (int qi=0;qi<2;qi++) { acc[ii][cm][qi][0]=0.f; acc[ii][cm][qi][1]=0.f;
                                       acc[ii][cm][qi][2]=0.f; acc[ii][cm][qi][3]=0.f; }
    float l[2][2] = {};

    // prologue: stage tile 0 -> buf 0 (async)
    gll16(kgb + (size_t)kjr*NC, KH + tid*8);
    gll16(vgb, VH + tid*8);
    if (w == 0) gll16(mgb, MI + lane*4);
    __syncthreads();

    int p = 0;
    for (int j0 = 0; j0 < NHW; j0 += 32) {
        int jn = (j0 + 32) & (NHW - 1);
        // async stage next tile -> buf p^1 (buffer stride 2048 f16 / 256 f32)
        gll16(kgb + (size_t)(jn + kjr)*NC, KH + (p^1)*2048 + tid*8);
        gll16(vgb + jn, VH + (p^1)*2048 + tid*8);
        if (w == 0) gll16(mgb + jn, MI + (p^1)*256 + lane*4);

        const f16* kh = KH + p*2048;
        const f16* vh = VH + p*2048;
        const float* mi = MI + p*256;
        // ---- scores, both instances (P' -> per-wave buffers) ----
#pragma unroll
        for (int jm = 0; jm < 2; ++jm) {
            int krow = jm*16 + l15;
            H8 ka0, ka1;
            ka0.u4 = *(const uint4*)&kh[krow*64 + ((quad       ^ (l15 & 7))*8)];
            ka1.u4 = *(const uint4*)&kh[krow*64 + (((4 + quad) ^ (l15 & 7))*8)];
#pragma unroll
            for (int ii = 0; ii < 2; ++ii) {
                floatx4 s0 = {0.f,0.f,0.f,0.f}, s1 = {0.f,0.f,0.f,0.f};
                s0 = __builtin_amdgcn_mfma_f32_16x16x32_f16(ka0.h8, qa[ii][0][0].h8, s0, 0, 0, 0);
                s0 = __builtin_amdgcn_mfma_f32_16x16x32_f16(ka1.h8, qa[ii][0][1].h8, s0, 0, 0, 0);
                s1 = __builtin_amdgcn_mfma_f32_16x16x32_f16(ka0.h8, qa[ii][1][0].h8, s1, 0, 0, 0);
                s1 = __builtin_amdgcn_mfma_f32_16x16x32_f16(ka1.h8, qa[ii][1][1].h8, s1, 0, 0, 0);
                float4 mj4 = *(const float4*)&mi[(i0+ii)*32 + jm*16 + quad*4];
                float mj[4] = {mj4.x, mj4.y, mj4.z, mj4.w};
                float p0[4], p1[4];
#pragma unroll
                for (int r = 0; r < 4; ++r) {
                    float e0 = __expf(s0[r]*(mj[r]*QSCI)); l[ii][0] += e0; p0[r] = e0*mj[r];
                    float e1 = __expf(s1[r]*(mj[r]*QSCI)); l[ii][1] += e1; p1[r] = e1*mj[r];
                }
                H4 pk0, pk1;
                pk0.h2[0] = __floats2half2_rn(p0[0], p0[1]);
                pk0.h2[1] = __floats2half2_rn(p0[2], p0[3]);
                pk1.h2[0] = __floats2half2_rn(p1[0], p1[1]);
                pk1.h2[1] = __floats2half2_rn(p1[2], p1[3]);
                f16* ph = PH + w*2560 + ii*1280;
                *(uint2*)&ph[l15*40      + jm*16 + quad*4] = pk0.u2;
                *(uint2*)&ph[(16+l15)*40 + jm*16 + quad*4] = pk1.u2;
            }
        }
        // ---- PV (same-wave LDS; in-order DS pipe, no barrier) ----
        H8 pb[2][2];
#pragma unroll
        for (int ii = 0; ii < 2; ++ii) {
            const f16* ph = PH + w*2560 + ii*1280;
            pb[ii][0].u4 = *(const uint4*)&ph[l15*40      + quad*8];
            pb[ii][1].u4 = *(const uint4*)&ph[(16+l15)*40 + quad*8];
        }
#pragma unroll
        for (int cm = 0; cm < 4; ++cm) {
            H8 va;
            va.u4 = *(const uint4*)&vh[(cm*16 + l15)*32 + ((quad ^ (l15 & 3))*8)];
            acc[0][cm][0] = __builtin_amdgcn_mfma_f32_16x16x32_f16(va.h8, pb[0][0].h8, acc[0][cm][0], 0, 0, 0);
            acc[0][cm][1] = __builtin_amdgcn_mfma_f32_16x16x32_f16(va.h8, pb[0][1].h8, acc[0][cm][1], 0, 0, 0);
            acc[1][cm][0] = __builtin_amdgcn_mfma_f32_16x16x32_f16(va.h8, pb[1][0].h8, acc[1][cm][0], 0, 0, 0);
            acc[1][cm][1] = __builtin_amdgcn_mfma_f32_16x16x32_f16(va.h8, pb[1][1].h8, acc[1][cm][1], 0, 0, 0);
        }
        __syncthreads();   // drains gll (next tile ready) + fences buffer reuse
        p ^= 1;
    }

    // ---- f = m_q/l (reduce over quads: lane bits 4,5) ----
    float f[2][2];
#pragma unroll
    for (int ii = 0; ii < 2; ++ii)
#pragma unroll
        for (int qi = 0; qi < 2; ++qi) {
            float lv = l[ii][qi];
            lv += __shfl_xor(lv, 16, 64);
            lv += __shfl_xor(lv, 32, 64);
            f[ii][qi] = mqf[ii][qi] / lv;
        }
    // ---- cross-instance 2-phase tree (overlay on KH/VH/MI region, dead after loop) ----
    float* bufA = (float*)lds;
    float* bufB = bufA + 2304;
    if (w < 2) {
        float* rb = w ? bufB : bufA;
#pragma unroll
        for (int cm = 0; cm < 4; ++cm)
#pragma unroll
            for (int qi = 0; qi < 2; ++qi)
#pragma unroll
                for (int r = 0; r < 4; ++r)
                    rb[(cm*16 + quad*4 + r)*36 + qi*16 + l15] =
                        f[0][qi]*acc[0][cm][qi][r] + f[1][qi]*acc[1][cm][qi][r];
    }
    __syncthreads();
    if (w >= 2) {
        float* rb = (w == 3) ? bufB : bufA;
#pragma unroll
        for (int cm = 0; cm < 4; ++cm)
#pragma unroll
            for (int qi = 0; qi < 2; ++qi)
#pragma unroll
                for (int r = 0; r < 4; ++r)
                    rb[(cm*16 + quad*4 + r)*36 + qi*16 + l15] +=
                        f[0][qi]*acc[0][cm][qi][r] + f[1][qi]*acc[1][cm][qi][r];
    }
    __syncthreads();
    int cc2 = tid >> 2, qg = (tid & 3)*8;
    float bvv = bv[c0 + cc2];
    float* op = out + ((size_t)(b*NC + c0 + cc2))*NHW + qt0;
#pragma unroll
    for (int t = 0; t < 2; ++t) {
        float4 va4 = *(const float4*)&bufA[cc2*36 + qg + t*4];
        float4 vb4 = *(const float4*)&bufB[cc2*36 + qg + t*4];
        float4 v;
        v.x = va4.x + vb4.x + bvv; v.y = va4.y + vb4.y + bvv;
        v.z = va4.z + vb4.z + bvv; v.w = va4.w + vb4.w + bvv;
        *(float4*)(op + qg + t*4) = v;
    }
}

extern "C" void kernel_launch(void* const* d_in, const int* in_sizes, int n_in,
                              void* d_out, int out_size, void* d_ws, size_t ws_size,
                              hipStream_t stream)
{
    const float* x      = (const float*)d_in[0];
    const float* w_inst = (const float*)d_in[1];
    const float* b_inst = (const float*)d_in[2];
    const float* wq = (const float*)d_in[3];
    const float* bq = (const float*)d_in[4];
    const float* wk = (const float*)d_in[5];
    const float* bk = (const float*)d_in[6];
    const float* wv = (const float*)d_in[7];
    const float* bv = (const float*)d_in[8];
    float* out = (float*)d_out;

    float* masks   = (float*)d_ws;                        // 8*8*1024 f32
    float* scale_q = masks + (size_t)NI*NB*NHW;           // 8*8*256
    float* scale_k = scale_q + (size_t)NI*NB*NC;
    f16*   Gqt     = (f16*)(scale_k + (size_t)NI*NB*NC);  // [b][n][c] f16
    f16*   Gkt     = Gqt + (size_t)NB*NHW*NC;             // [b][n][c] f16
    f16*   Gv      = Gkt + (size_t)NB*NHW*NC;             // [b][c][n] f16
    f16*   xt      = Gv + (size_t)NB*NC*NHW;              // [b][n][c] f16
    float* part_m  = (float*)(xt + (size_t)NB*NHW*NC);    // 8*8*8*1024
    float* part_nq = part_m + (size_t)8*NI*NB*NHW;        // 32*8*8*256
    float* part_nk = part_nq + (size_t)32*NI*NB*NC;

    k_mask_part<<<dim3(4, NB, 8), 256, 0, stream>>>(x, w_inst, part_m, xt);
    k_gemm_mfma<<<dim3(8, 4, 24), 256, 0, stream>>>(xt, wq, wk, wv, Gqt, Gkt, Gv);
    k_norm_mask<<<dim3(32, NB), 256, 0, stream>>>(part_m, b_inst, Gqt, Gkt, bq, bk,
                                                  masks, part_nq, part_nk);
    k_norm_fin<<<dim3(NB, NI), 256, 0, stream>>>(part_nq, part_nk, scale_q, scale_k);
    k_attn7<<<dim3(1024), 256, 0, stream>>>(Gqt, Gkt, Gv, masks, bq, bv,
                                            scale_q, scale_k, out);
}